// Round 4
// baseline (1091.311 us; speedup 1.0000x reference)
//
#include <hip/hip_runtime.h>
#include <math.h>

// pGNN on MI355X. N=100000, E=1.6M, IN=256, HID=64, OUT=40. MU=0.1, P=2.5, K=2.
// Round 4: k_mlp1 rewritten lane=col / 16 rows-per-wave / x via scalar (SMEM)
// loads. Round 3's mlp1 was latency-bound (VALUBusy 12%, 2.4M LDS conflicts):
// per-k global W1 load + LDS broadcast gave 4 FMAs per 2 waited loads. New
// form: w is one coalesced 256B load/k, x[row][k] is wave-uniform -> s_load
// on the scalar pipe (forced via readfirstlane), 16 v_fmac_f32 per k.

#define HIDC 64
#define RPW 16   // rows per wave in k_mlp1

// ---------------- degree ----------------
__global__ void k_deg(const int* __restrict__ col, int* __restrict__ deg, int E) {
    int e = blockIdx.x * blockDim.x + threadIdx.x;
    if (e < E) atomicAdd(&deg[col[e]], 1);
}

// ---------------- per-node: dis + CSR segment alloc (bump allocator) ----------------
__global__ void k_nodeinit(const int* __restrict__ deg, float* __restrict__ dis,
                           int* __restrict__ off, int* __restrict__ cursor,
                           int* __restrict__ counter, int N) {
    int i = blockIdx.x * blockDim.x + threadIdx.x;
    if (i < N) {
        int d = deg[i];
        dis[i] = (d > 0) ? rsqrtf((float)d) : 0.0f;
        int o = atomicAdd(counter, d);
        off[i] = o;
        cursor[i] = o;
    }
}

// ---------------- CSR fill ----------------
__global__ void k_fill(const int* __restrict__ row, const int* __restrict__ col,
                       int* __restrict__ cursor, int* __restrict__ csr_src, int E) {
    int e = blockIdx.x * blockDim.x + threadIdx.x;
    if (e < E) {
        int pos = atomicAdd(&cursor[col[e]], 1);
        csr_src[pos] = row[e];
    }
}

// ---------------- h = relu(x @ W1 + b1); sh = dis*h ----------------
// lane = output column; wave handles RPW consecutive rows.
__global__ void k_mlp1(const float* __restrict__ x, const float* __restrict__ W1,
                       const float* __restrict__ b1, const float* __restrict__ dis,
                       float* __restrict__ h, float* __restrict__ sh, int N) {
    const int lane = threadIdx.x & 63;
    // wave-uniform row base, forced into SGPR so x loads hit the scalar pipe
    int waveInBlk = __builtin_amdgcn_readfirstlane(threadIdx.x >> 6);
    int wave = blockIdx.x * (blockDim.x >> 6) + waveInBlk;
    int rowBase = wave * RPW;
    if (rowBase >= N) return;

    // clamped per-row base pointers (all SGPR-resident, computed once)
    const float* xr[RPW];
    #pragma unroll
    for (int r = 0; r < RPW; ++r) {
        int row = rowBase + r;
        if (row > N - 1) row = N - 1;
        xr[r] = x + (size_t)row * 256;
    }

    float acc[RPW];
    const float bc = b1[lane];
    #pragma unroll
    for (int r = 0; r < RPW; ++r) acc[r] = bc;

    #pragma unroll 4
    for (int k = 0; k < 256; ++k) {
        float w = W1[k * HIDC + lane];      // coalesced 256B vector load
        #pragma unroll
        for (int r = 0; r < RPW; ++r)
            acc[r] = fmaf(xr[r][k], w, acc[r]);   // s_load x + v_fmac
    }

    #pragma unroll
    for (int r = 0; r < RPW; ++r) {
        int row = rowBase + r;
        if (row < N) {
            float hv = fmaxf(acc[r], 0.f);
            float dr = dis[row];
            h[(size_t)row * HIDC + lane]  = hv;
            sh[(size_t)row * HIDC + lane] = hv * dr;
        }
    }
}

// ---------------- calc_M: wave per dest node, 4 edges/step, float4 dims ----------------
__global__ void k_calcM(const int* __restrict__ csr_src, const int* __restrict__ off,
                        const int* __restrict__ deg, const float* __restrict__ dis,
                        const float* __restrict__ scur, float* __restrict__ Mcsr,
                        float* __restrict__ alphaArr, int N) {
    int wave = (int)((blockIdx.x * (size_t)blockDim.x + threadIdx.x) >> 6);
    int lane = threadIdx.x & 63;
    if (wave >= N) return;
    const int c = wave;
    const int o = off[c];
    const int dg = deg[c];
    const int g = lane >> 4;     // edge group 0..3
    const int t = lane & 15;     // dim quad
    const float dc = dis[c];
    const float4 sc = *(const float4*)(scur + (size_t)c * HIDC + t * 4);
    float seg = 0.0f;
    for (int j = 0; j < dg; j += 4) {
        int jj = j + g;
        bool valid = jj < dg;
        int r = valid ? csr_src[o + jj] : c;     // r=c -> diff 0 for pad lanes
        const float4 sr = *(const float4*)(scur + (size_t)r * HIDC + t * 4);
        float dx = sr.x - sc.x, dy = sr.y - sc.y, dz = sr.z - sc.z, dw = sr.w - sc.w;
        float s = fmaf(dx, dx, fmaf(dy, dy, fmaf(dz, dz, dw * dw)));
        s += __shfl_xor(s, 1, 64);
        s += __shfl_xor(s, 2, 64);
        s += __shfl_xor(s, 4, 64);
        s += __shfl_xor(s, 8, 64);
        float m = sqrtf(sqrtf(s));               // grad_norm^(P-2), P=2.5
        if (isinf(m)) m = 0.0f;
        if (valid) {
            if (t == 0) Mcsr[o + jj] = m;
            seg += m;
        }
    }
    seg += __shfl_xor(seg, 16, 64);
    seg += __shfl_xor(seg, 32, 64);
    if (lane == 0) alphaArr[c] = 1.0f / (dc * dc * seg + 0.08f);   // 2*MU/P
}

// ---------------- gather: out[c] = beta*h[c] + sum (alpha[r]*M*dc) * scur[r] ----------------
__global__ void k_gather(const int* __restrict__ csr_src, const int* __restrict__ off,
                         const int* __restrict__ deg, const float* __restrict__ dis,
                         const float* __restrict__ alphaArr, const float* __restrict__ Mcsr,
                         const float* __restrict__ scur, const float* __restrict__ h,
                         float* __restrict__ outNext, float* __restrict__ soutNext, int N) {
    int wave = (int)((blockIdx.x * (size_t)blockDim.x + threadIdx.x) >> 6);
    int lane = threadIdx.x & 63;
    if (wave >= N) return;
    const int c = wave;
    const int o = off[c];
    const int dg = deg[c];
    const int g = lane >> 4;
    const int t = lane & 15;
    const float dc = dis[c];
    float4 acc = make_float4(0.f, 0.f, 0.f, 0.f);
    for (int j = 0; j < dg; j += 4) {
        int jj = j + g;
        bool valid = jj < dg;
        int r = valid ? csr_src[o + jj] : c;
        float coef = valid ? (alphaArr[r] * Mcsr[o + jj] * dc) : 0.0f;
        const float4 sr = *(const float4*)(scur + (size_t)r * HIDC + t * 4);
        acc.x = fmaf(coef, sr.x, acc.x);
        acc.y = fmaf(coef, sr.y, acc.y);
        acc.z = fmaf(coef, sr.z, acc.z);
        acc.w = fmaf(coef, sr.w, acc.w);
    }
    acc.x += __shfl_xor(acc.x, 16, 64);
    acc.y += __shfl_xor(acc.y, 16, 64);
    acc.z += __shfl_xor(acc.z, 16, 64);
    acc.w += __shfl_xor(acc.w, 16, 64);
    acc.x += __shfl_xor(acc.x, 32, 64);
    acc.y += __shfl_xor(acc.y, 32, 64);
    acc.z += __shfl_xor(acc.z, 32, 64);
    acc.w += __shfl_xor(acc.w, 32, 64);
    if (g == 0) {
        float ba = 0.16f * alphaArr[c];          // beta = 4*MU/P * alpha
        const float4 hv = *(const float4*)(h + (size_t)c * HIDC + t * 4);
        float4 ov;
        ov.x = fmaf(ba, hv.x, acc.x);
        ov.y = fmaf(ba, hv.y, acc.y);
        ov.z = fmaf(ba, hv.z, acc.z);
        ov.w = fmaf(ba, hv.w, acc.w);
        if (outNext)  *(float4*)(outNext  + (size_t)c * HIDC + t * 4) = ov;
        if (soutNext) {
            float4 sv = make_float4(ov.x * dc, ov.y * dc, ov.z * dc, ov.w * dc);
            *(float4*)(soutNext + (size_t)c * HIDC + t * 4) = sv;
        }
    }
}

// ---------------- head: log_softmax(out @ W2 + b2) ----------------
__global__ void k_head(const float* __restrict__ out, const float* __restrict__ W2,
                       const float* __restrict__ b2, float* __restrict__ y,
                       int N, int OUT) {
    int wave = (int)((blockIdx.x * (size_t)blockDim.x + threadIdx.x) >> 6);
    int lane = threadIdx.x & 63;
    if (wave >= N) return;
    float acc = 0.0f;
    if (lane < OUT) {
        acc = b2[lane];
        #pragma unroll 8
        for (int k = 0; k < HIDC; ++k)
            acc = fmaf(out[(size_t)wave * HIDC + k], W2[k * OUT + lane], acc);
    }
    float v = (lane < OUT) ? acc : -INFINITY;
    #pragma unroll
    for (int sh = 32; sh; sh >>= 1) v = fmaxf(v, __shfl_xor(v, sh, 64));
    float ex = (lane < OUT) ? __expf(acc - v) : 0.0f;
    float s = ex;
    #pragma unroll
    for (int sh = 32; sh; sh >>= 1) s += __shfl_xor(s, sh, 64);
    if (lane < OUT) y[(size_t)wave * OUT + lane] = acc - v - __logf(s);
}

extern "C" void kernel_launch(void* const* d_in, const int* in_sizes, int n_in,
                              void* d_out, int out_size, void* d_ws, size_t ws_size,
                              hipStream_t stream) {
    const float* x  = (const float*)d_in[0];
    const int*   ei = (const int*)d_in[1];
    const float* W1 = (const float*)d_in[2];
    const float* b1 = (const float*)d_in[3];
    const float* W2 = (const float*)d_in[4];
    const float* b2 = (const float*)d_in[5];
    float* y = (float*)d_out;

    const int HID = in_sizes[3];            // 64
    const int IN  = in_sizes[2] / HID;      // 256
    const int OUT = in_sizes[5];            // 40
    const int N   = in_sizes[0] / IN;       // 100000
    const int E   = in_sizes[1] / 2;        // 1.6M
    const int* rowI = ei;
    const int* colI = ei + E;

    // workspace carve-up
    float* p = (float*)d_ws;
    float* dis   = p;  p += N;
    float* alpha = p;  p += N;
    float* Mcsr  = p;  p += E;
    float* h     = p;  p += (size_t)N * HID;   // raw MLP out (beta term, both iters)
    float* sh    = p;  p += (size_t)N * HID;   // dis*h; reused as final out2
    float* sA    = p;  p += (size_t)N * HID;   // dis*out1
    int*   deg     = (int*)p;  p += N;
    int*   off     = (int*)p;  p += N;
    int*   cursor  = (int*)p;  p += N;
    int*   counter = (int*)p;  p += 1;
    int*   csr_src = (int*)p;  p += E;
    float* out2 = sh;                          // sh dead after iter-1 gather

    const int TPB = 256;
    const int edgeBlocks     = (E + TPB - 1) / TPB;
    const int nodeBlocks     = (N + TPB - 1) / TPB;
    const int nodeWaveBlocks = (N + 3) / 4;    // 4 waves/block, wave per node

    // CSR build
    hipMemsetAsync(deg, 0, sizeof(int) * N, stream);
    hipMemsetAsync(counter, 0, sizeof(int), stream);
    k_deg<<<edgeBlocks, TPB, 0, stream>>>(colI, deg, E);
    k_nodeinit<<<nodeBlocks, TPB, 0, stream>>>(deg, dis, off, cursor, counter, N);
    k_fill<<<edgeBlocks, TPB, 0, stream>>>(rowI, colI, cursor, csr_src, E);

    // front MLP (writes h and sh = dis*h); wave = RPW rows, 4 waves/block
    {
        int waves = (N + RPW - 1) / RPW;
        int blocks = (waves + 3) / 4;
        k_mlp1<<<blocks, TPB, 0, stream>>>(x, W1, b1, dis, h, sh, N);
    }

    // iteration 1: scur = sh -> writes only sA (raw out1 never consumed)
    k_calcM<<<nodeWaveBlocks, TPB, 0, stream>>>(csr_src, off, deg, dis, sh, Mcsr, alpha, N);
    k_gather<<<nodeWaveBlocks, TPB, 0, stream>>>(csr_src, off, deg, dis, alpha, Mcsr,
                                                 sh, h, (float*)nullptr, sA, N);

    // iteration 2: scur = sA -> writes raw out2 (into sh's storage)
    k_calcM<<<nodeWaveBlocks, TPB, 0, stream>>>(csr_src, off, deg, dis, sA, Mcsr, alpha, N);
    k_gather<<<nodeWaveBlocks, TPB, 0, stream>>>(csr_src, off, deg, dis, alpha, Mcsr,
                                                 sA, h, out2, (float*)nullptr, N);

    // output head
    k_head<<<nodeWaveBlocks, TPB, 0, stream>>>(out2, W2, b2, y, N, OUT);
}

// Round 5
// 954.171 us; speedup vs baseline: 1.1437x; 1.1437x over previous
//
#include <hip/hip_runtime.h>
#include <math.h>

// pGNN on MI355X. N=100000, E=1.6M, IN=256, HID=64, OUT=40. MU=0.1, P=2.5, K=2.
// Round 5: k_mlp1 v3 — lane=row, acc[64] cols in VGPRs, W1 row per k via the
// scalar pipe (wave-uniform s_load_dwordx16 of a single hot shared 64KB array),
// x as per-lane float4 stream. Round 4's mistake: 16 cold strided scalar
// streams of x; scalar pipe only works for one shared sequential stream.
// Round 3's LDS version was L1-BW bound (1KB W1 through L1 per 8 FMA-cycles).

#define HIDC 64

// ---------------- degree ----------------
__global__ void k_deg(const int* __restrict__ col, int* __restrict__ deg, int E) {
    int e = blockIdx.x * blockDim.x + threadIdx.x;
    if (e < E) atomicAdd(&deg[col[e]], 1);
}

// ---------------- per-node: dis + CSR segment alloc (bump allocator) ----------------
__global__ void k_nodeinit(const int* __restrict__ deg, float* __restrict__ dis,
                           int* __restrict__ off, int* __restrict__ cursor,
                           int* __restrict__ counter, int N) {
    int i = blockIdx.x * blockDim.x + threadIdx.x;
    if (i < N) {
        int d = deg[i];
        dis[i] = (d > 0) ? rsqrtf((float)d) : 0.0f;
        int o = atomicAdd(counter, d);
        off[i] = o;
        cursor[i] = o;
    }
}

// ---------------- CSR fill ----------------
__global__ void k_fill(const int* __restrict__ row, const int* __restrict__ col,
                       int* __restrict__ cursor, int* __restrict__ csr_src, int E) {
    int e = blockIdx.x * blockDim.x + threadIdx.x;
    if (e < E) {
        int pos = atomicAdd(&cursor[col[e]], 1);
        csr_src[pos] = row[e];
    }
}

// ---------------- h = relu(x @ W1 + b1); sh = dis*h ----------------
// lane = row; thread accumulates all 64 output columns in registers.
// W1[k][*] is wave-uniform -> scalar loads; x[row][k] per-lane float4 stream.
__global__ void k_mlp1(const float* __restrict__ x, const float* __restrict__ W1,
                       const float* __restrict__ b1, const float* __restrict__ dis,
                       float* __restrict__ h, float* __restrict__ sh, int N) {
    const int lane = threadIdx.x & 63;
    int waveInBlk = __builtin_amdgcn_readfirstlane(threadIdx.x >> 6);
    int wave = blockIdx.x * (blockDim.x >> 6) + waveInBlk;
    int row = wave * 64 + lane;
    const bool active = row < N;
    const float* xr = x + (size_t)(active ? row : (N - 1)) * 256;

    float acc[HIDC];
    #pragma unroll
    for (int c = 0; c < HIDC; ++c) acc[c] = b1[c];   // uniform -> s_load

    float4 xv = *(const float4*)(xr);
    for (int k = 0; k < 256; k += 4) {
        float4 xn;
        if (k + 4 < 256) xn = *(const float4*)(xr + k + 4);   // prefetch
        #pragma unroll
        for (int kk = 0; kk < 4; ++kk) {
            const float xs_ = (kk == 0) ? xv.x : (kk == 1) ? xv.y : (kk == 2) ? xv.z : xv.w;
            const float* wrow = W1 + (k + kk) * HIDC;          // wave-uniform
            #pragma unroll
            for (int c = 0; c < HIDC; ++c)
                acc[c] = fmaf(xs_, wrow[c], acc[c]);           // v_fmac v, s, v
        }
        xv = xn;
    }

    if (active) {
        float dr = dis[row];
        float* hp  = h  + (size_t)row * HIDC;
        float* shp = sh + (size_t)row * HIDC;
        #pragma unroll
        for (int c = 0; c < HIDC; c += 4) {
            float4 hv;
            hv.x = fmaxf(acc[c],     0.f);
            hv.y = fmaxf(acc[c + 1], 0.f);
            hv.z = fmaxf(acc[c + 2], 0.f);
            hv.w = fmaxf(acc[c + 3], 0.f);
            *(float4*)(hp + c) = hv;
            float4 sv = make_float4(hv.x * dr, hv.y * dr, hv.z * dr, hv.w * dr);
            *(float4*)(shp + c) = sv;
        }
    }
}

// ---------------- calc_M: wave per dest node, 4 edges/step, float4 dims ----------------
__global__ void k_calcM(const int* __restrict__ csr_src, const int* __restrict__ off,
                        const int* __restrict__ deg, const float* __restrict__ dis,
                        const float* __restrict__ scur, float* __restrict__ Mcsr,
                        float* __restrict__ alphaArr, int N) {
    int wave = (int)((blockIdx.x * (size_t)blockDim.x + threadIdx.x) >> 6);
    int lane = threadIdx.x & 63;
    if (wave >= N) return;
    const int c = wave;
    const int o = off[c];
    const int dg = deg[c];
    const int g = lane >> 4;     // edge group 0..3
    const int t = lane & 15;     // dim quad
    const float dc = dis[c];
    const float4 sc = *(const float4*)(scur + (size_t)c * HIDC + t * 4);
    float seg = 0.0f;
    for (int j = 0; j < dg; j += 4) {
        int jj = j + g;
        bool valid = jj < dg;
        int r = valid ? csr_src[o + jj] : c;     // r=c -> diff 0 for pad lanes
        const float4 sr = *(const float4*)(scur + (size_t)r * HIDC + t * 4);
        float dx = sr.x - sc.x, dy = sr.y - sc.y, dz = sr.z - sc.z, dw = sr.w - sc.w;
        float s = fmaf(dx, dx, fmaf(dy, dy, fmaf(dz, dz, dw * dw)));
        s += __shfl_xor(s, 1, 64);
        s += __shfl_xor(s, 2, 64);
        s += __shfl_xor(s, 4, 64);
        s += __shfl_xor(s, 8, 64);
        float m = sqrtf(sqrtf(s));               // grad_norm^(P-2), P=2.5
        if (isinf(m)) m = 0.0f;
        if (valid) {
            if (t == 0) Mcsr[o + jj] = m;
            seg += m;
        }
    }
    seg += __shfl_xor(seg, 16, 64);
    seg += __shfl_xor(seg, 32, 64);
    if (lane == 0) alphaArr[c] = 1.0f / (dc * dc * seg + 0.08f);   // 2*MU/P
}

// ---------------- gather: out[c] = beta*h[c] + sum (alpha[r]*M*dc) * scur[r] ----------------
__global__ void k_gather(const int* __restrict__ csr_src, const int* __restrict__ off,
                         const int* __restrict__ deg, const float* __restrict__ dis,
                         const float* __restrict__ alphaArr, const float* __restrict__ Mcsr,
                         const float* __restrict__ scur, const float* __restrict__ h,
                         float* __restrict__ outNext, float* __restrict__ soutNext, int N) {
    int wave = (int)((blockIdx.x * (size_t)blockDim.x + threadIdx.x) >> 6);
    int lane = threadIdx.x & 63;
    if (wave >= N) return;
    const int c = wave;
    const int o = off[c];
    const int dg = deg[c];
    const int g = lane >> 4;
    const int t = lane & 15;
    const float dc = dis[c];
    float4 acc = make_float4(0.f, 0.f, 0.f, 0.f);
    for (int j = 0; j < dg; j += 4) {
        int jj = j + g;
        bool valid = jj < dg;
        int r = valid ? csr_src[o + jj] : c;
        float coef = valid ? (alphaArr[r] * Mcsr[o + jj] * dc) : 0.0f;
        const float4 sr = *(const float4*)(scur + (size_t)r * HIDC + t * 4);
        acc.x = fmaf(coef, sr.x, acc.x);
        acc.y = fmaf(coef, sr.y, acc.y);
        acc.z = fmaf(coef, sr.z, acc.z);
        acc.w = fmaf(coef, sr.w, acc.w);
    }
    acc.x += __shfl_xor(acc.x, 16, 64);
    acc.y += __shfl_xor(acc.y, 16, 64);
    acc.z += __shfl_xor(acc.z, 16, 64);
    acc.w += __shfl_xor(acc.w, 16, 64);
    acc.x += __shfl_xor(acc.x, 32, 64);
    acc.y += __shfl_xor(acc.y, 32, 64);
    acc.z += __shfl_xor(acc.z, 32, 64);
    acc.w += __shfl_xor(acc.w, 32, 64);
    if (g == 0) {
        float ba = 0.16f * alphaArr[c];          // beta = 4*MU/P * alpha
        const float4 hv = *(const float4*)(h + (size_t)c * HIDC + t * 4);
        float4 ov;
        ov.x = fmaf(ba, hv.x, acc.x);
        ov.y = fmaf(ba, hv.y, acc.y);
        ov.z = fmaf(ba, hv.z, acc.z);
        ov.w = fmaf(ba, hv.w, acc.w);
        if (outNext)  *(float4*)(outNext  + (size_t)c * HIDC + t * 4) = ov;
        if (soutNext) {
            float4 sv = make_float4(ov.x * dc, ov.y * dc, ov.z * dc, ov.w * dc);
            *(float4*)(soutNext + (size_t)c * HIDC + t * 4) = sv;
        }
    }
}

// ---------------- head: log_softmax(out @ W2 + b2) ----------------
__global__ void k_head(const float* __restrict__ out, const float* __restrict__ W2,
                       const float* __restrict__ b2, float* __restrict__ y,
                       int N, int OUT) {
    int wave = (int)((blockIdx.x * (size_t)blockDim.x + threadIdx.x) >> 6);
    int lane = threadIdx.x & 63;
    if (wave >= N) return;
    float acc = 0.0f;
    if (lane < OUT) {
        acc = b2[lane];
        #pragma unroll 8
        for (int k = 0; k < HIDC; ++k)
            acc = fmaf(out[(size_t)wave * HIDC + k], W2[k * OUT + lane], acc);
    }
    float v = (lane < OUT) ? acc : -INFINITY;
    #pragma unroll
    for (int sh = 32; sh; sh >>= 1) v = fmaxf(v, __shfl_xor(v, sh, 64));
    float ex = (lane < OUT) ? __expf(acc - v) : 0.0f;
    float s = ex;
    #pragma unroll
    for (int sh = 32; sh; sh >>= 1) s += __shfl_xor(s, sh, 64);
    if (lane < OUT) y[(size_t)wave * OUT + lane] = acc - v - __logf(s);
}

extern "C" void kernel_launch(void* const* d_in, const int* in_sizes, int n_in,
                              void* d_out, int out_size, void* d_ws, size_t ws_size,
                              hipStream_t stream) {
    const float* x  = (const float*)d_in[0];
    const int*   ei = (const int*)d_in[1];
    const float* W1 = (const float*)d_in[2];
    const float* b1 = (const float*)d_in[3];
    const float* W2 = (const float*)d_in[4];
    const float* b2 = (const float*)d_in[5];
    float* y = (float*)d_out;

    const int HID = in_sizes[3];            // 64
    const int IN  = in_sizes[2] / HID;      // 256
    const int OUT = in_sizes[5];            // 40
    const int N   = in_sizes[0] / IN;       // 100000
    const int E   = in_sizes[1] / 2;        // 1.6M
    const int* rowI = ei;
    const int* colI = ei + E;

    // workspace carve-up
    float* p = (float*)d_ws;
    float* dis   = p;  p += N;
    float* alpha = p;  p += N;
    float* Mcsr  = p;  p += E;
    float* h     = p;  p += (size_t)N * HID;   // raw MLP out (beta term, both iters)
    float* sh    = p;  p += (size_t)N * HID;   // dis*h; reused as final out2
    float* sA    = p;  p += (size_t)N * HID;   // dis*out1
    int*   deg     = (int*)p;  p += N;
    int*   off     = (int*)p;  p += N;
    int*   cursor  = (int*)p;  p += N;
    int*   counter = (int*)p;  p += 1;
    int*   csr_src = (int*)p;  p += E;
    float* out2 = sh;                          // sh dead after iter-1 gather

    const int TPB = 256;
    const int edgeBlocks     = (E + TPB - 1) / TPB;
    const int nodeBlocks     = (N + TPB - 1) / TPB;
    const int nodeWaveBlocks = (N + 3) / 4;    // 4 waves/block, wave per node

    // CSR build
    hipMemsetAsync(deg, 0, sizeof(int) * N, stream);
    hipMemsetAsync(counter, 0, sizeof(int), stream);
    k_deg<<<edgeBlocks, TPB, 0, stream>>>(colI, deg, E);
    k_nodeinit<<<nodeBlocks, TPB, 0, stream>>>(deg, dis, off, cursor, counter, N);
    k_fill<<<edgeBlocks, TPB, 0, stream>>>(rowI, colI, cursor, csr_src, E);

    // front MLP (writes h and sh = dis*h); wave = 64 rows, 4 waves/block
    {
        int waves = (N + 63) / 64;
        int blocks = (waves + 3) / 4;
        k_mlp1<<<blocks, TPB, 0, stream>>>(x, W1, b1, dis, h, sh, N);
    }

    // iteration 1: scur = sh -> writes only sA (raw out1 never consumed)
    k_calcM<<<nodeWaveBlocks, TPB, 0, stream>>>(csr_src, off, deg, dis, sh, Mcsr, alpha, N);
    k_gather<<<nodeWaveBlocks, TPB, 0, stream>>>(csr_src, off, deg, dis, alpha, Mcsr,
                                                 sh, h, (float*)nullptr, sA, N);

    // iteration 2: scur = sA -> writes raw out2 (into sh's storage)
    k_calcM<<<nodeWaveBlocks, TPB, 0, stream>>>(csr_src, off, deg, dis, sA, Mcsr, alpha, N);
    k_gather<<<nodeWaveBlocks, TPB, 0, stream>>>(csr_src, off, deg, dis, alpha, Mcsr,
                                                 sA, h, out2, (float*)nullptr, N);

    // output head
    k_head<<<nodeWaveBlocks, TPB, 0, stream>>>(out2, W2, b2, y, N, OUT);
}

// Round 6
// 864.174 us; speedup vs baseline: 1.2628x; 1.1041x over previous
//
#include <hip/hip_runtime.h>
#include <math.h>

// pGNN on MI355X. N=100000, E=1.6M, IN=256, HID=64, OUT=40. MU=0.1, P=2.5, K=2.
// Round 6: k_mlp1 v4 — W1 staged whole in LDS (64KB), register tile 8 rows x
// 4 cols per thread (acc=32: round 5's acc[64] spilled to scratch, VGPR=44 +
// 43MB extra WRITE). 782 blocks restores occupancy (round 5: 1.5 waves/SIMD).
// Per k: 1 ds_read_b128 (w) + amortized x float4 -> 32 FMAs/thread: issue-bound.

#define HIDC 64
#define TROWS 128   // rows per block tile
#define RPT 8       // rows per thread
#define CPT 4       // cols per thread

// ---------------- degree ----------------
__global__ void k_deg(const int* __restrict__ col, int* __restrict__ deg, int E) {
    int e = blockIdx.x * blockDim.x + threadIdx.x;
    if (e < E) atomicAdd(&deg[col[e]], 1);
}

// ---------------- per-node: dis + CSR segment alloc (bump allocator) ----------------
__global__ void k_nodeinit(const int* __restrict__ deg, float* __restrict__ dis,
                           int* __restrict__ off, int* __restrict__ cursor,
                           int* __restrict__ counter, int N) {
    int i = blockIdx.x * blockDim.x + threadIdx.x;
    if (i < N) {
        int d = deg[i];
        dis[i] = (d > 0) ? rsqrtf((float)d) : 0.0f;
        int o = atomicAdd(counter, d);
        off[i] = o;
        cursor[i] = o;
    }
}

// ---------------- CSR fill ----------------
__global__ void k_fill(const int* __restrict__ row, const int* __restrict__ col,
                       int* __restrict__ cursor, int* __restrict__ csr_src, int E) {
    int e = blockIdx.x * blockDim.x + threadIdx.x;
    if (e < E) {
        int pos = atomicAdd(&cursor[col[e]], 1);
        csr_src[pos] = row[e];
    }
}

// ---------------- h = relu(x @ W1 + b1); sh = dis*h ----------------
// W1 (256x64 f32 = 64KB) fully staged in LDS; thread tile = 8 rows x 4 cols.
__global__ void k_mlp1(const float* __restrict__ x, const float* __restrict__ W1,
                       const float* __restrict__ b1, const float* __restrict__ dis,
                       float* __restrict__ h, float* __restrict__ sh, int N) {
    __shared__ float ws[256 * HIDC];       // 64 KB
    const int tid = threadIdx.x;

    // stage W1: 4096 float4 slots, 16 per thread, fully coalesced
    {
        const float4* src = (const float4*)W1;
        float4* dst = (float4*)ws;
        #pragma unroll
        for (int i = 0; i < 16; ++i)
            dst[tid + 256 * i] = src[tid + 256 * i];
    }
    __syncthreads();

    const int c0 = (tid & 15) * CPT;          // col base 0..60
    const int r0 = (tid >> 4) * RPT;          // row-in-tile base 0..120
    const int rowBase = blockIdx.x * TROWS + r0;

    // clamped per-row x pointers
    const float* xp[RPT];
    #pragma unroll
    for (int r = 0; r < RPT; ++r) {
        int rr = rowBase + r;
        if (rr > N - 1) rr = N - 1;
        xp[r] = x + (size_t)rr * 256;
    }

    float acc[RPT][CPT];
    {
        const float4 bv = *(const float4*)(b1 + c0);
        #pragma unroll
        for (int r = 0; r < RPT; ++r) {
            acc[r][0] = bv.x; acc[r][1] = bv.y; acc[r][2] = bv.z; acc[r][3] = bv.w;
        }
    }

    for (int k0 = 0; k0 < 256; k0 += 4) {
        float4 xv[RPT];
        #pragma unroll
        for (int r = 0; r < RPT; ++r) xv[r] = *(const float4*)(xp[r] + k0);
        #pragma unroll
        for (int kk = 0; kk < 4; ++kk) {
            const float4 wv = *(const float4*)(ws + (k0 + kk) * HIDC + c0);
            #pragma unroll
            for (int r = 0; r < RPT; ++r) {
                const float xs_ = (kk == 0) ? xv[r].x : (kk == 1) ? xv[r].y
                                : (kk == 2) ? xv[r].z : xv[r].w;
                acc[r][0] = fmaf(xs_, wv.x, acc[r][0]);
                acc[r][1] = fmaf(xs_, wv.y, acc[r][1]);
                acc[r][2] = fmaf(xs_, wv.z, acc[r][2]);
                acc[r][3] = fmaf(xs_, wv.w, acc[r][3]);
            }
        }
    }

    #pragma unroll
    for (int r = 0; r < RPT; ++r) {
        int row = rowBase + r;
        if (row < N) {
            float dr = dis[row];
            float4 hv;
            hv.x = fmaxf(acc[r][0], 0.f);
            hv.y = fmaxf(acc[r][1], 0.f);
            hv.z = fmaxf(acc[r][2], 0.f);
            hv.w = fmaxf(acc[r][3], 0.f);
            *(float4*)(h + (size_t)row * HIDC + c0) = hv;
            float4 sv = make_float4(hv.x * dr, hv.y * dr, hv.z * dr, hv.w * dr);
            *(float4*)(sh + (size_t)row * HIDC + c0) = sv;
        }
    }
}

// ---------------- calc_M: wave per dest node, 4 edges/step, float4 dims ----------------
__global__ void k_calcM(const int* __restrict__ csr_src, const int* __restrict__ off,
                        const int* __restrict__ deg, const float* __restrict__ dis,
                        const float* __restrict__ scur, float* __restrict__ Mcsr,
                        float* __restrict__ alphaArr, int N) {
    int wave = (int)((blockIdx.x * (size_t)blockDim.x + threadIdx.x) >> 6);
    int lane = threadIdx.x & 63;
    if (wave >= N) return;
    const int c = wave;
    const int o = off[c];
    const int dg = deg[c];
    const int g = lane >> 4;     // edge group 0..3
    const int t = lane & 15;     // dim quad
    const float dc = dis[c];
    const float4 sc = *(const float4*)(scur + (size_t)c * HIDC + t * 4);
    float seg = 0.0f;
    for (int j = 0; j < dg; j += 4) {
        int jj = j + g;
        bool valid = jj < dg;
        int r = valid ? csr_src[o + jj] : c;     // r=c -> diff 0 for pad lanes
        const float4 sr = *(const float4*)(scur + (size_t)r * HIDC + t * 4);
        float dx = sr.x - sc.x, dy = sr.y - sc.y, dz = sr.z - sc.z, dw = sr.w - sc.w;
        float s = fmaf(dx, dx, fmaf(dy, dy, fmaf(dz, dz, dw * dw)));
        s += __shfl_xor(s, 1, 64);
        s += __shfl_xor(s, 2, 64);
        s += __shfl_xor(s, 4, 64);
        s += __shfl_xor(s, 8, 64);
        float m = sqrtf(sqrtf(s));               // grad_norm^(P-2), P=2.5
        if (isinf(m)) m = 0.0f;
        if (valid) {
            if (t == 0) Mcsr[o + jj] = m;
            seg += m;
        }
    }
    seg += __shfl_xor(seg, 16, 64);
    seg += __shfl_xor(seg, 32, 64);
    if (lane == 0) alphaArr[c] = 1.0f / (dc * dc * seg + 0.08f);   // 2*MU/P
}

// ---------------- gather: out[c] = beta*h[c] + sum (alpha[r]*M*dc) * scur[r] ----------------
__global__ void k_gather(const int* __restrict__ csr_src, const int* __restrict__ off,
                         const int* __restrict__ deg, const float* __restrict__ dis,
                         const float* __restrict__ alphaArr, const float* __restrict__ Mcsr,
                         const float* __restrict__ scur, const float* __restrict__ h,
                         float* __restrict__ outNext, float* __restrict__ soutNext, int N) {
    int wave = (int)((blockIdx.x * (size_t)blockDim.x + threadIdx.x) >> 6);
    int lane = threadIdx.x & 63;
    if (wave >= N) return;
    const int c = wave;
    const int o = off[c];
    const int dg = deg[c];
    const int g = lane >> 4;
    const int t = lane & 15;
    const float dc = dis[c];
    float4 acc = make_float4(0.f, 0.f, 0.f, 0.f);
    for (int j = 0; j < dg; j += 4) {
        int jj = j + g;
        bool valid = jj < dg;
        int r = valid ? csr_src[o + jj] : c;
        float coef = valid ? (alphaArr[r] * Mcsr[o + jj] * dc) : 0.0f;
        const float4 sr = *(const float4*)(scur + (size_t)r * HIDC + t * 4);
        acc.x = fmaf(coef, sr.x, acc.x);
        acc.y = fmaf(coef, sr.y, acc.y);
        acc.z = fmaf(coef, sr.z, acc.z);
        acc.w = fmaf(coef, sr.w, acc.w);
    }
    acc.x += __shfl_xor(acc.x, 16, 64);
    acc.y += __shfl_xor(acc.y, 16, 64);
    acc.z += __shfl_xor(acc.z, 16, 64);
    acc.w += __shfl_xor(acc.w, 16, 64);
    acc.x += __shfl_xor(acc.x, 32, 64);
    acc.y += __shfl_xor(acc.y, 32, 64);
    acc.z += __shfl_xor(acc.z, 32, 64);
    acc.w += __shfl_xor(acc.w, 32, 64);
    if (g == 0) {
        float ba = 0.16f * alphaArr[c];          // beta = 4*MU/P * alpha
        const float4 hv = *(const float4*)(h + (size_t)c * HIDC + t * 4);
        float4 ov;
        ov.x = fmaf(ba, hv.x, acc.x);
        ov.y = fmaf(ba, hv.y, acc.y);
        ov.z = fmaf(ba, hv.z, acc.z);
        ov.w = fmaf(ba, hv.w, acc.w);
        if (outNext)  *(float4*)(outNext  + (size_t)c * HIDC + t * 4) = ov;
        if (soutNext) {
            float4 sv = make_float4(ov.x * dc, ov.y * dc, ov.z * dc, ov.w * dc);
            *(float4*)(soutNext + (size_t)c * HIDC + t * 4) = sv;
        }
    }
}

// ---------------- head: log_softmax(out @ W2 + b2) ----------------
__global__ void k_head(const float* __restrict__ out, const float* __restrict__ W2,
                       const float* __restrict__ b2, float* __restrict__ y,
                       int N, int OUT) {
    int wave = (int)((blockIdx.x * (size_t)blockDim.x + threadIdx.x) >> 6);
    int lane = threadIdx.x & 63;
    if (wave >= N) return;
    float acc = 0.0f;
    if (lane < OUT) {
        acc = b2[lane];
        #pragma unroll 8
        for (int k = 0; k < HIDC; ++k)
            acc = fmaf(out[(size_t)wave * HIDC + k], W2[k * OUT + lane], acc);
    }
    float v = (lane < OUT) ? acc : -INFINITY;
    #pragma unroll
    for (int sh = 32; sh; sh >>= 1) v = fmaxf(v, __shfl_xor(v, sh, 64));
    float ex = (lane < OUT) ? __expf(acc - v) : 0.0f;
    float s = ex;
    #pragma unroll
    for (int sh = 32; sh; sh >>= 1) s += __shfl_xor(s, sh, 64);
    if (lane < OUT) y[(size_t)wave * OUT + lane] = acc - v - __logf(s);
}

extern "C" void kernel_launch(void* const* d_in, const int* in_sizes, int n_in,
                              void* d_out, int out_size, void* d_ws, size_t ws_size,
                              hipStream_t stream) {
    const float* x  = (const float*)d_in[0];
    const int*   ei = (const int*)d_in[1];
    const float* W1 = (const float*)d_in[2];
    const float* b1 = (const float*)d_in[3];
    const float* W2 = (const float*)d_in[4];
    const float* b2 = (const float*)d_in[5];
    float* y = (float*)d_out;

    const int HID = in_sizes[3];            // 64
    const int IN  = in_sizes[2] / HID;      // 256
    const int OUT = in_sizes[5];            // 40
    const int N   = in_sizes[0] / IN;       // 100000
    const int E   = in_sizes[1] / 2;        // 1.6M
    const int* rowI = ei;
    const int* colI = ei + E;

    // workspace carve-up
    float* p = (float*)d_ws;
    float* dis   = p;  p += N;
    float* alpha = p;  p += N;
    float* Mcsr  = p;  p += E;
    float* h     = p;  p += (size_t)N * HID;   // raw MLP out (beta term, both iters)
    float* sh    = p;  p += (size_t)N * HID;   // dis*h; reused as final out2
    float* sA    = p;  p += (size_t)N * HID;   // dis*out1
    int*   deg     = (int*)p;  p += N;
    int*   off     = (int*)p;  p += N;
    int*   cursor  = (int*)p;  p += N;
    int*   counter = (int*)p;  p += 1;
    int*   csr_src = (int*)p;  p += E;
    float* out2 = sh;                          // sh dead after iter-1 gather

    const int TPB = 256;
    const int edgeBlocks     = (E + TPB - 1) / TPB;
    const int nodeBlocks     = (N + TPB - 1) / TPB;
    const int nodeWaveBlocks = (N + 3) / 4;    // 4 waves/block, wave per node

    // CSR build
    hipMemsetAsync(deg, 0, sizeof(int) * N, stream);
    hipMemsetAsync(counter, 0, sizeof(int), stream);
    k_deg<<<edgeBlocks, TPB, 0, stream>>>(colI, deg, E);
    k_nodeinit<<<nodeBlocks, TPB, 0, stream>>>(deg, dis, off, cursor, counter, N);
    k_fill<<<edgeBlocks, TPB, 0, stream>>>(rowI, colI, cursor, csr_src, E);

    // front MLP (writes h and sh = dis*h); 128-row tile per block
    k_mlp1<<<(N + TROWS - 1) / TROWS, TPB, 0, stream>>>(x, W1, b1, dis, h, sh, N);

    // iteration 1: scur = sh -> writes only sA (raw out1 never consumed)
    k_calcM<<<nodeWaveBlocks, TPB, 0, stream>>>(csr_src, off, deg, dis, sh, Mcsr, alpha, N);
    k_gather<<<nodeWaveBlocks, TPB, 0, stream>>>(csr_src, off, deg, dis, alpha, Mcsr,
                                                 sh, h, (float*)nullptr, sA, N);

    // iteration 2: scur = sA -> writes raw out2 (into sh's storage)
    k_calcM<<<nodeWaveBlocks, TPB, 0, stream>>>(csr_src, off, deg, dis, sA, Mcsr, alpha, N);
    k_gather<<<nodeWaveBlocks, TPB, 0, stream>>>(csr_src, off, deg, dis, alpha, Mcsr,
                                                 sA, h, out2, (float*)nullptr, N);

    // output head
    k_head<<<nodeWaveBlocks, TPB, 0, stream>>>(out2, W2, b2, y, N, OUT);
}

// Round 7
// 801.040 us; speedup vs baseline: 1.3624x; 1.0788x over previous
//
#include <hip/hip_runtime.h>
#include <math.h>

// pGNN on MI355X. N=100000, E=1.6M, IN=256, HID=64, OUT=40. MU=0.1, P=2.5, K=2.
// Round 7: CSR fill rewritten region-grouped. Round 6's k_fill had WRITE_SIZE
// 105MB for a 6.4MB payload (one 64B writeback per 4B random store — lines
// evicted before filling, shared across XCDs). New: exclusive-scan offsets
// (node-ordered => region-contiguous csr), fill kernel with 8 groups
// (g = blockIdx%8 ~ XCD), group g only handles col region g => single-XCD
// ownership of each 800KB csr window + cursor window; lines fill before evict.

#define HIDC 64
#define TROWS 128   // rows per block tile (mlp1)
#define RPT 8       // rows per thread
#define CPT 4       // cols per thread
#define FILL_CH 4096  // edges per fill block chunk

// ---------------- degree ----------------
__global__ void k_deg(const int* __restrict__ col, int* __restrict__ deg, int E) {
    int e = blockIdx.x * blockDim.x + threadIdx.x;
    if (e < E) atomicAdd(&deg[col[e]], 1);
}

// ---------------- block exclusive scan helper (256 threads) ----------------
__device__ inline void blockExScan256(int v, int tid, int* ex_out, int* tot_out,
                                      volatile int* wsum) {
    int lane = tid & 63, w = tid >> 6;
    int inc = v;
    #pragma unroll
    for (int d = 1; d < 64; d <<= 1) {
        int t = __shfl_up(inc, d, 64);
        if (lane >= d) inc += t;
    }
    if (lane == 63) wsum[w] = inc;
    __syncthreads();
    int wbase = 0;
    #pragma unroll
    for (int k = 0; k < 4; ++k) if (k < w) wbase += wsum[k];
    *ex_out = wbase + inc - v;
    *tot_out = wsum[0] + wsum[1] + wsum[2] + wsum[3];
    __syncthreads();   // safe for caller to reuse wsum after return
}

// ---------------- scan stage A: per-block sums of deg ----------------
__global__ void k_scanA(const int* __restrict__ deg, int* __restrict__ bsum, int N) {
    __shared__ int wsum[4];
    int i = blockIdx.x * blockDim.x + threadIdx.x;
    int v = (i < N) ? deg[i] : 0;
    int ex, tot;
    blockExScan256(v, threadIdx.x, &ex, &tot, wsum);
    if (threadIdx.x == 0) bsum[blockIdx.x] = tot;
}

// ---------------- scan stage B: scan the block sums in-place ----------------
__global__ void k_scanB(int* __restrict__ bsum, int nb) {
    __shared__ int wsum[4];
    __shared__ int carry;
    if (threadIdx.x == 0) carry = 0;
    __syncthreads();
    for (int base = 0; base < nb; base += 256) {
        int i = base + threadIdx.x;
        int v = (i < nb) ? bsum[i] : 0;
        int ex, tot;
        blockExScan256(v, threadIdx.x, &ex, &tot, wsum);
        int c = carry;
        if (i < nb) bsum[i] = c + ex;
        __syncthreads();
        if (threadIdx.x == 0) carry = c + tot;
        __syncthreads();
    }
}

// ---------------- scan stage C: off/cursor/dis (fused nodeinit) ----------------
__global__ void k_scanC(const int* __restrict__ deg, const int* __restrict__ bsum,
                        float* __restrict__ dis, int* __restrict__ off,
                        int* __restrict__ cursor, int N) {
    __shared__ int wsum[4];
    int i = blockIdx.x * blockDim.x + threadIdx.x;
    int d = (i < N) ? deg[i] : 0;
    int ex, tot;
    blockExScan256(d, threadIdx.x, &ex, &tot, wsum);
    if (i < N) {
        int o = bsum[blockIdx.x] + ex;
        off[i] = o;
        cursor[i] = o;
        dis[i] = (d > 0) ? rsqrtf((float)d) : 0.0f;
    }
}

// ---------------- CSR fill, region-grouped ----------------
// group g = blockIdx%8 (XCD heuristic) handles only cols with col/regDiv == g.
__global__ void k_fill2(const int* __restrict__ row, const int* __restrict__ col,
                        int* __restrict__ cursor, int* __restrict__ csr_src,
                        int E, int regDiv) {
    const int g = blockIdx.x & 7;
    const int base = (blockIdx.x >> 3) * FILL_CH;
    #pragma unroll 4
    for (int i = threadIdx.x; i < FILL_CH; i += 256) {
        int e = base + i;
        if (e < E) {
            int c = col[e];
            if (c / regDiv == g) {
                int pos = atomicAdd(&cursor[c], 1);
                csr_src[pos] = row[e];
            }
        }
    }
}

// ---------------- h = relu(x @ W1 + b1); sh = dis*h ----------------
__global__ void k_mlp1(const float* __restrict__ x, const float* __restrict__ W1,
                       const float* __restrict__ b1, const float* __restrict__ dis,
                       float* __restrict__ h, float* __restrict__ sh, int N) {
    __shared__ float ws[256 * HIDC];       // 64 KB
    const int tid = threadIdx.x;
    {
        const float4* src = (const float4*)W1;
        float4* dst = (float4*)ws;
        #pragma unroll
        for (int i = 0; i < 16; ++i)
            dst[tid + 256 * i] = src[tid + 256 * i];
    }
    __syncthreads();

    const int c0 = (tid & 15) * CPT;
    const int r0 = (tid >> 4) * RPT;
    const int rowBase = blockIdx.x * TROWS + r0;

    const float* xp[RPT];
    #pragma unroll
    for (int r = 0; r < RPT; ++r) {
        int rr = rowBase + r;
        if (rr > N - 1) rr = N - 1;
        xp[r] = x + (size_t)rr * 256;
    }

    float acc[RPT][CPT];
    {
        const float4 bv = *(const float4*)(b1 + c0);
        #pragma unroll
        for (int r = 0; r < RPT; ++r) {
            acc[r][0] = bv.x; acc[r][1] = bv.y; acc[r][2] = bv.z; acc[r][3] = bv.w;
        }
    }

    for (int k0 = 0; k0 < 256; k0 += 4) {
        float4 xv[RPT];
        #pragma unroll
        for (int r = 0; r < RPT; ++r) xv[r] = *(const float4*)(xp[r] + k0);
        #pragma unroll
        for (int kk = 0; kk < 4; ++kk) {
            const float4 wv = *(const float4*)(ws + (k0 + kk) * HIDC + c0);
            #pragma unroll
            for (int r = 0; r < RPT; ++r) {
                const float xs_ = (kk == 0) ? xv[r].x : (kk == 1) ? xv[r].y
                                : (kk == 2) ? xv[r].z : xv[r].w;
                acc[r][0] = fmaf(xs_, wv.x, acc[r][0]);
                acc[r][1] = fmaf(xs_, wv.y, acc[r][1]);
                acc[r][2] = fmaf(xs_, wv.z, acc[r][2]);
                acc[r][3] = fmaf(xs_, wv.w, acc[r][3]);
            }
        }
    }

    #pragma unroll
    for (int r = 0; r < RPT; ++r) {
        int row = rowBase + r;
        if (row < N) {
            float dr = dis[row];
            float4 hv;
            hv.x = fmaxf(acc[r][0], 0.f);
            hv.y = fmaxf(acc[r][1], 0.f);
            hv.z = fmaxf(acc[r][2], 0.f);
            hv.w = fmaxf(acc[r][3], 0.f);
            *(float4*)(h + (size_t)row * HIDC + c0) = hv;
            float4 sv = make_float4(hv.x * dr, hv.y * dr, hv.z * dr, hv.w * dr);
            *(float4*)(sh + (size_t)row * HIDC + c0) = sv;
        }
    }
}

// ---------------- calc_M: wave per dest node, 4 edges/step, float4 dims ----------------
__global__ void k_calcM(const int* __restrict__ csr_src, const int* __restrict__ off,
                        const int* __restrict__ deg, const float* __restrict__ dis,
                        const float* __restrict__ scur, float* __restrict__ Mcsr,
                        float* __restrict__ alphaArr, int N) {
    int wave = (int)((blockIdx.x * (size_t)blockDim.x + threadIdx.x) >> 6);
    int lane = threadIdx.x & 63;
    if (wave >= N) return;
    const int c = wave;
    const int o = off[c];
    const int dg = deg[c];
    const int g = lane >> 4;     // edge group 0..3
    const int t = lane & 15;     // dim quad
    const float dc = dis[c];
    const float4 sc = *(const float4*)(scur + (size_t)c * HIDC + t * 4);
    float seg = 0.0f;
    for (int j = 0; j < dg; j += 4) {
        int jj = j + g;
        bool valid = jj < dg;
        int r = valid ? csr_src[o + jj] : c;     // r=c -> diff 0 for pad lanes
        const float4 sr = *(const float4*)(scur + (size_t)r * HIDC + t * 4);
        float dx = sr.x - sc.x, dy = sr.y - sc.y, dz = sr.z - sc.z, dw = sr.w - sc.w;
        float s = fmaf(dx, dx, fmaf(dy, dy, fmaf(dz, dz, dw * dw)));
        s += __shfl_xor(s, 1, 64);
        s += __shfl_xor(s, 2, 64);
        s += __shfl_xor(s, 4, 64);
        s += __shfl_xor(s, 8, 64);
        float m = sqrtf(sqrtf(s));               // grad_norm^(P-2), P=2.5
        if (isinf(m)) m = 0.0f;
        if (valid) {
            if (t == 0) Mcsr[o + jj] = m;
            seg += m;
        }
    }
    seg += __shfl_xor(seg, 16, 64);
    seg += __shfl_xor(seg, 32, 64);
    if (lane == 0) alphaArr[c] = 1.0f / (dc * dc * seg + 0.08f);   // 2*MU/P
}

// ---------------- gather: out[c] = beta*h[c] + sum (alpha[r]*M*dc) * scur[r] ----------------
__global__ void k_gather(const int* __restrict__ csr_src, const int* __restrict__ off,
                         const int* __restrict__ deg, const float* __restrict__ dis,
                         const float* __restrict__ alphaArr, const float* __restrict__ Mcsr,
                         const float* __restrict__ scur, const float* __restrict__ h,
                         float* __restrict__ outNext, float* __restrict__ soutNext, int N) {
    int wave = (int)((blockIdx.x * (size_t)blockDim.x + threadIdx.x) >> 6);
    int lane = threadIdx.x & 63;
    if (wave >= N) return;
    const int c = wave;
    const int o = off[c];
    const int dg = deg[c];
    const int g = lane >> 4;
    const int t = lane & 15;
    const float dc = dis[c];
    float4 acc = make_float4(0.f, 0.f, 0.f, 0.f);
    for (int j = 0; j < dg; j += 4) {
        int jj = j + g;
        bool valid = jj < dg;
        int r = valid ? csr_src[o + jj] : c;
        float coef = valid ? (alphaArr[r] * Mcsr[o + jj] * dc) : 0.0f;
        const float4 sr = *(const float4*)(scur + (size_t)r * HIDC + t * 4);
        acc.x = fmaf(coef, sr.x, acc.x);
        acc.y = fmaf(coef, sr.y, acc.y);
        acc.z = fmaf(coef, sr.z, acc.z);
        acc.w = fmaf(coef, sr.w, acc.w);
    }
    acc.x += __shfl_xor(acc.x, 16, 64);
    acc.y += __shfl_xor(acc.y, 16, 64);
    acc.z += __shfl_xor(acc.z, 16, 64);
    acc.w += __shfl_xor(acc.w, 16, 64);
    acc.x += __shfl_xor(acc.x, 32, 64);
    acc.y += __shfl_xor(acc.y, 32, 64);
    acc.z += __shfl_xor(acc.z, 32, 64);
    acc.w += __shfl_xor(acc.w, 32, 64);
    if (g == 0) {
        float ba = 0.16f * alphaArr[c];          // beta = 4*MU/P * alpha
        const float4 hv = *(const float4*)(h + (size_t)c * HIDC + t * 4);
        float4 ov;
        ov.x = fmaf(ba, hv.x, acc.x);
        ov.y = fmaf(ba, hv.y, acc.y);
        ov.z = fmaf(ba, hv.z, acc.z);
        ov.w = fmaf(ba, hv.w, acc.w);
        if (outNext)  *(float4*)(outNext  + (size_t)c * HIDC + t * 4) = ov;
        if (soutNext) {
            float4 sv = make_float4(ov.x * dc, ov.y * dc, ov.z * dc, ov.w * dc);
            *(float4*)(soutNext + (size_t)c * HIDC + t * 4) = sv;
        }
    }
}

// ---------------- head: log_softmax(out @ W2 + b2) ----------------
__global__ void k_head(const float* __restrict__ out, const float* __restrict__ W2,
                       const float* __restrict__ b2, float* __restrict__ y,
                       int N, int OUT) {
    int wave = (int)((blockIdx.x * (size_t)blockDim.x + threadIdx.x) >> 6);
    int lane = threadIdx.x & 63;
    if (wave >= N) return;
    float acc = 0.0f;
    if (lane < OUT) {
        acc = b2[lane];
        #pragma unroll 8
        for (int k = 0; k < HIDC; ++k)
            acc = fmaf(out[(size_t)wave * HIDC + k], W2[k * OUT + lane], acc);
    }
    float v = (lane < OUT) ? acc : -INFINITY;
    #pragma unroll
    for (int sh = 32; sh; sh >>= 1) v = fmaxf(v, __shfl_xor(v, sh, 64));
    float ex = (lane < OUT) ? __expf(acc - v) : 0.0f;
    float s = ex;
    #pragma unroll
    for (int sh = 32; sh; sh >>= 1) s += __shfl_xor(s, sh, 64);
    if (lane < OUT) y[(size_t)wave * OUT + lane] = acc - v - __logf(s);
}

extern "C" void kernel_launch(void* const* d_in, const int* in_sizes, int n_in,
                              void* d_out, int out_size, void* d_ws, size_t ws_size,
                              hipStream_t stream) {
    const float* x  = (const float*)d_in[0];
    const int*   ei = (const int*)d_in[1];
    const float* W1 = (const float*)d_in[2];
    const float* b1 = (const float*)d_in[3];
    const float* W2 = (const float*)d_in[4];
    const float* b2 = (const float*)d_in[5];
    float* y = (float*)d_out;

    const int HID = in_sizes[3];            // 64
    const int IN  = in_sizes[2] / HID;      // 256
    const int OUT = in_sizes[5];            // 40
    const int N   = in_sizes[0] / IN;       // 100000
    const int E   = in_sizes[1] / 2;        // 1.6M
    const int* rowI = ei;
    const int* colI = ei + E;

    // workspace carve-up
    float* p = (float*)d_ws;
    float* dis   = p;  p += N;
    float* alpha = p;  p += N;
    float* Mcsr  = p;  p += E;
    float* h     = p;  p += (size_t)N * HID;   // raw MLP out (beta term, both iters)
    float* sh    = p;  p += (size_t)N * HID;   // dis*h; reused as final out2
    float* sA    = p;  p += (size_t)N * HID;   // dis*out1
    int*   deg     = (int*)p;  p += N;
    int*   off     = (int*)p;  p += N;
    int*   cursor  = (int*)p;  p += N;
    int*   csr_src = (int*)p;  p += E;
    int*   bsum    = (int*)p;  p += (N + 255) / 256;
    float* out2 = sh;                          // sh dead after iter-1 gather

    const int TPB = 256;
    const int edgeBlocks = (E + TPB - 1) / TPB;
    const int nodeBlocks = (N + TPB - 1) / TPB;
    const int nodeWaveBlocks = (N + 3) / 4;    // 4 waves/block, wave per node
    const int regDiv = (N + 7) / 8;            // 12500: col/regDiv = region 0..7

    // CSR build: deg -> exclusive scan (node-ordered offsets) -> region fill
    hipMemsetAsync(deg, 0, sizeof(int) * N, stream);
    k_deg<<<edgeBlocks, TPB, 0, stream>>>(colI, deg, E);
    k_scanA<<<nodeBlocks, TPB, 0, stream>>>(deg, bsum, N);
    k_scanB<<<1, TPB, 0, stream>>>(bsum, nodeBlocks);
    k_scanC<<<nodeBlocks, TPB, 0, stream>>>(deg, bsum, dis, off, cursor, N);
    {
        int nch = (E + FILL_CH - 1) / FILL_CH;
        k_fill2<<<8 * nch, TPB, 0, stream>>>(rowI, colI, cursor, csr_src, E, regDiv);
    }

    // front MLP (writes h and sh = dis*h); 128-row tile per block
    k_mlp1<<<(N + TROWS - 1) / TROWS, TPB, 0, stream>>>(x, W1, b1, dis, h, sh, N);

    // iteration 1: scur = sh -> writes only sA (raw out1 never consumed)
    k_calcM<<<nodeWaveBlocks, TPB, 0, stream>>>(csr_src, off, deg, dis, sh, Mcsr, alpha, N);
    k_gather<<<nodeWaveBlocks, TPB, 0, stream>>>(csr_src, off, deg, dis, alpha, Mcsr,
                                                 sh, h, (float*)nullptr, sA, N);

    // iteration 2: scur = sA -> writes raw out2 (into sh's storage)
    k_calcM<<<nodeWaveBlocks, TPB, 0, stream>>>(csr_src, off, deg, dis, sA, Mcsr, alpha, N);
    k_gather<<<nodeWaveBlocks, TPB, 0, stream>>>(csr_src, off, deg, dis, alpha, Mcsr,
                                                 sA, h, out2, (float*)nullptr, N);

    // output head
    k_head<<<nodeWaveBlocks, TPB, 0, stream>>>(out2, W2, b2, y, N, OUT);
}

// Round 8
// 800.301 us; speedup vs baseline: 1.3636x; 1.0009x over previous
//
#include <hip/hip_runtime.h>
#include <math.h>

// pGNN on MI355X. N=100000, E=1.6M, IN=256, HID=64, OUT=40. MU=0.1, P=2.5, K=2.
// Round 8: (a) mlp1 v5 stages W1 in two 32KB halves -> 4 blocks/CU (round 7:
// 64KB LDS capped at 2 blocks/CU, Occ 15%, VALUBusy 26%); (b) scur (dis*feat)
// stored bf16 -> calcM/gather row gathers halve from 256B to 128B/row
// (~820 MB/iter of L2/L3 traffic was the aggregate floor). Norm math in f32.

#define HIDC 64
#define TROWS 128   // rows per block tile (mlp1)
#define RPT 8       // rows per thread
#define CPT 4       // cols per thread
#define FILL_CH 4096

typedef unsigned short u16;

__device__ inline u16 f2bf(float f) {
    union { float f; unsigned int u; } v; v.f = f;
    unsigned int u = v.u;
    u += 0x7FFFu + ((u >> 16) & 1u);     // round-to-nearest-even
    return (u16)(u >> 16);
}
__device__ inline float bf2f(u16 b) {
    union { unsigned int u; float f; } v; v.u = ((unsigned int)b) << 16;
    return v.f;
}

// ---------------- degree ----------------
__global__ void k_deg(const int* __restrict__ col, int* __restrict__ deg, int E) {
    int e = blockIdx.x * blockDim.x + threadIdx.x;
    if (e < E) atomicAdd(&deg[col[e]], 1);
}

// ---------------- block exclusive scan helper (256 threads) ----------------
__device__ inline void blockExScan256(int v, int tid, int* ex_out, int* tot_out,
                                      volatile int* wsum) {
    int lane = tid & 63, w = tid >> 6;
    int inc = v;
    #pragma unroll
    for (int d = 1; d < 64; d <<= 1) {
        int t = __shfl_up(inc, d, 64);
        if (lane >= d) inc += t;
    }
    if (lane == 63) wsum[w] = inc;
    __syncthreads();
    int wbase = 0;
    #pragma unroll
    for (int k = 0; k < 4; ++k) if (k < w) wbase += wsum[k];
    *ex_out = wbase + inc - v;
    *tot_out = wsum[0] + wsum[1] + wsum[2] + wsum[3];
    __syncthreads();
}

__global__ void k_scanA(const int* __restrict__ deg, int* __restrict__ bsum, int N) {
    __shared__ int wsum[4];
    int i = blockIdx.x * blockDim.x + threadIdx.x;
    int v = (i < N) ? deg[i] : 0;
    int ex, tot;
    blockExScan256(v, threadIdx.x, &ex, &tot, wsum);
    if (threadIdx.x == 0) bsum[blockIdx.x] = tot;
}

__global__ void k_scanB(int* __restrict__ bsum, int nb) {
    __shared__ int wsum[4];
    __shared__ int carry;
    if (threadIdx.x == 0) carry = 0;
    __syncthreads();
    for (int base = 0; base < nb; base += 256) {
        int i = base + threadIdx.x;
        int v = (i < nb) ? bsum[i] : 0;
        int ex, tot;
        blockExScan256(v, threadIdx.x, &ex, &tot, wsum);
        int c = carry;
        if (i < nb) bsum[i] = c + ex;
        __syncthreads();
        if (threadIdx.x == 0) carry = c + tot;
        __syncthreads();
    }
}

__global__ void k_scanC(const int* __restrict__ deg, const int* __restrict__ bsum,
                        float* __restrict__ dis, int* __restrict__ off,
                        int* __restrict__ cursor, int N) {
    __shared__ int wsum[4];
    int i = blockIdx.x * blockDim.x + threadIdx.x;
    int d = (i < N) ? deg[i] : 0;
    int ex, tot;
    blockExScan256(d, threadIdx.x, &ex, &tot, wsum);
    if (i < N) {
        int o = bsum[blockIdx.x] + ex;
        off[i] = o;
        cursor[i] = o;
        dis[i] = (d > 0) ? rsqrtf((float)d) : 0.0f;
    }
}

// ---------------- CSR fill, region-grouped (XCD locality) ----------------
__global__ void k_fill2(const int* __restrict__ row, const int* __restrict__ col,
                        int* __restrict__ cursor, int* __restrict__ csr_src,
                        int E, int regDiv) {
    const int g = blockIdx.x & 7;
    const int base = (blockIdx.x >> 3) * FILL_CH;
    #pragma unroll 4
    for (int i = threadIdx.x; i < FILL_CH; i += 256) {
        int e = base + i;
        if (e < E) {
            int c = col[e];
            if (c / regDiv == g) {
                int pos = atomicAdd(&cursor[c], 1);
                csr_src[pos] = row[e];
            }
        }
    }
}

// ---------------- h = relu(x @ W1 + b1); sh_bf = bf16(dis*h) ----------------
// W1 staged in two 32KB halves (4 blocks/CU); thread tile 8 rows x 4 cols.
__global__ void k_mlp1(const float* __restrict__ x, const float* __restrict__ W1,
                       const float* __restrict__ b1, const float* __restrict__ dis,
                       float* __restrict__ h, u16* __restrict__ sh_bf, int N) {
    __shared__ float ws[128 * HIDC];       // 32 KB
    const int tid = threadIdx.x;
    const int c0 = (tid & 15) * CPT;
    const int r0 = (tid >> 4) * RPT;
    const int rowBase = blockIdx.x * TROWS + r0;

    const float* xp[RPT];
    #pragma unroll
    for (int r = 0; r < RPT; ++r) {
        int rr = rowBase + r;
        if (rr > N - 1) rr = N - 1;
        xp[r] = x + (size_t)rr * 256;
    }

    float acc[RPT][CPT];
    {
        const float4 bv = *(const float4*)(b1 + c0);
        #pragma unroll
        for (int r = 0; r < RPT; ++r) {
            acc[r][0] = bv.x; acc[r][1] = bv.y; acc[r][2] = bv.z; acc[r][3] = bv.w;
        }
    }

    for (int half = 0; half < 2; ++half) {
        if (half) __syncthreads();         // protect prior half's reads
        {
            const float4* src = (const float4*)(W1 + half * 128 * HIDC);
            float4* dst = (float4*)ws;
            #pragma unroll
            for (int i = 0; i < 8; ++i)
                dst[tid + 256 * i] = src[tid + 256 * i];
        }
        __syncthreads();
        const int kb = half * 128;
        for (int k0 = 0; k0 < 128; k0 += 4) {
            float4 xv[RPT];
            #pragma unroll
            for (int r = 0; r < RPT; ++r) xv[r] = *(const float4*)(xp[r] + kb + k0);
            #pragma unroll
            for (int kk = 0; kk < 4; ++kk) {
                const float4 wv = *(const float4*)(ws + (k0 + kk) * HIDC + c0);
                #pragma unroll
                for (int r = 0; r < RPT; ++r) {
                    const float xs_ = (kk == 0) ? xv[r].x : (kk == 1) ? xv[r].y
                                    : (kk == 2) ? xv[r].z : xv[r].w;
                    acc[r][0] = fmaf(xs_, wv.x, acc[r][0]);
                    acc[r][1] = fmaf(xs_, wv.y, acc[r][1]);
                    acc[r][2] = fmaf(xs_, wv.z, acc[r][2]);
                    acc[r][3] = fmaf(xs_, wv.w, acc[r][3]);
                }
            }
        }
    }

    #pragma unroll
    for (int r = 0; r < RPT; ++r) {
        int row = rowBase + r;
        if (row < N) {
            float dr = dis[row];
            float4 hv;
            hv.x = fmaxf(acc[r][0], 0.f);
            hv.y = fmaxf(acc[r][1], 0.f);
            hv.z = fmaxf(acc[r][2], 0.f);
            hv.w = fmaxf(acc[r][3], 0.f);
            *(float4*)(h + (size_t)row * HIDC + c0) = hv;
            ushort4 sv;
            sv.x = f2bf(hv.x * dr); sv.y = f2bf(hv.y * dr);
            sv.z = f2bf(hv.z * dr); sv.w = f2bf(hv.w * dr);
            *(ushort4*)(sh_bf + (size_t)row * HIDC + c0) = sv;
        }
    }
}

// ---------------- calc_M: wave per dest node, 4 edges/step, bf16 rows ----------------
__global__ void k_calcM(const int* __restrict__ csr_src, const int* __restrict__ off,
                        const int* __restrict__ deg, const float* __restrict__ dis,
                        const u16* __restrict__ scur, float* __restrict__ Mcsr,
                        float* __restrict__ alphaArr, int N) {
    int wave = (int)((blockIdx.x * (size_t)blockDim.x + threadIdx.x) >> 6);
    int lane = threadIdx.x & 63;
    if (wave >= N) return;
    const int c = wave;
    const int o = off[c];
    const int dg = deg[c];
    const int g = lane >> 4;     // edge group 0..3
    const int t = lane & 15;     // dim quad
    const float dc = dis[c];
    const ushort4 scb = *(const ushort4*)(scur + (size_t)c * HIDC + t * 4);
    const float scx = bf2f(scb.x), scy = bf2f(scb.y), scz = bf2f(scb.z), scw = bf2f(scb.w);
    float seg = 0.0f;
    for (int j = 0; j < dg; j += 4) {
        int jj = j + g;
        bool valid = jj < dg;
        int r = valid ? csr_src[o + jj] : c;     // r=c -> diff 0 for pad lanes
        const ushort4 srb = *(const ushort4*)(scur + (size_t)r * HIDC + t * 4);
        float dx = bf2f(srb.x) - scx, dy = bf2f(srb.y) - scy;
        float dz = bf2f(srb.z) - scz, dw = bf2f(srb.w) - scw;
        float s = fmaf(dx, dx, fmaf(dy, dy, fmaf(dz, dz, dw * dw)));
        s += __shfl_xor(s, 1, 64);
        s += __shfl_xor(s, 2, 64);
        s += __shfl_xor(s, 4, 64);
        s += __shfl_xor(s, 8, 64);
        float m = sqrtf(sqrtf(s));               // grad_norm^(P-2), P=2.5
        if (isinf(m)) m = 0.0f;
        if (valid) {
            if (t == 0) Mcsr[o + jj] = m;
            seg += m;
        }
    }
    seg += __shfl_xor(seg, 16, 64);
    seg += __shfl_xor(seg, 32, 64);
    if (lane == 0) alphaArr[c] = 1.0f / (dc * dc * seg + 0.08f);   // 2*MU/P
}

// ---------------- gather: out[c] = beta*h[c] + sum (alpha[r]*M*dc) * scur[r] ----------------
// outNext (f32) and/or soutNext (bf16 = dis*out); either may be null.
__global__ void k_gather(const int* __restrict__ csr_src, const int* __restrict__ off,
                         const int* __restrict__ deg, const float* __restrict__ dis,
                         const float* __restrict__ alphaArr, const float* __restrict__ Mcsr,
                         const u16* __restrict__ scur, const float* __restrict__ h,
                         float* __restrict__ outNext, u16* __restrict__ soutNext, int N) {
    int wave = (int)((blockIdx.x * (size_t)blockDim.x + threadIdx.x) >> 6);
    int lane = threadIdx.x & 63;
    if (wave >= N) return;
    const int c = wave;
    const int o = off[c];
    const int dg = deg[c];
    const int g = lane >> 4;
    const int t = lane & 15;
    const float dc = dis[c];
    float4 acc = make_float4(0.f, 0.f, 0.f, 0.f);
    for (int j = 0; j < dg; j += 4) {
        int jj = j + g;
        bool valid = jj < dg;
        int r = valid ? csr_src[o + jj] : c;
        float coef = valid ? (alphaArr[r] * Mcsr[o + jj] * dc) : 0.0f;
        const ushort4 srb = *(const ushort4*)(scur + (size_t)r * HIDC + t * 4);
        acc.x = fmaf(coef, bf2f(srb.x), acc.x);
        acc.y = fmaf(coef, bf2f(srb.y), acc.y);
        acc.z = fmaf(coef, bf2f(srb.z), acc.z);
        acc.w = fmaf(coef, bf2f(srb.w), acc.w);
    }
    acc.x += __shfl_xor(acc.x, 16, 64);
    acc.y += __shfl_xor(acc.y, 16, 64);
    acc.z += __shfl_xor(acc.z, 16, 64);
    acc.w += __shfl_xor(acc.w, 16, 64);
    acc.x += __shfl_xor(acc.x, 32, 64);
    acc.y += __shfl_xor(acc.y, 32, 64);
    acc.z += __shfl_xor(acc.z, 32, 64);
    acc.w += __shfl_xor(acc.w, 32, 64);
    if (g == 0) {
        float ba = 0.16f * alphaArr[c];          // beta = 4*MU/P * alpha
        const float4 hv = *(const float4*)(h + (size_t)c * HIDC + t * 4);
        float4 ov;
        ov.x = fmaf(ba, hv.x, acc.x);
        ov.y = fmaf(ba, hv.y, acc.y);
        ov.z = fmaf(ba, hv.z, acc.z);
        ov.w = fmaf(ba, hv.w, acc.w);
        if (outNext)  *(float4*)(outNext + (size_t)c * HIDC + t * 4) = ov;
        if (soutNext) {
            ushort4 sv;
            sv.x = f2bf(ov.x * dc); sv.y = f2bf(ov.y * dc);
            sv.z = f2bf(ov.z * dc); sv.w = f2bf(ov.w * dc);
            *(ushort4*)(soutNext + (size_t)c * HIDC + t * 4) = sv;
        }
    }
}

// ---------------- head: log_softmax(out @ W2 + b2) ----------------
__global__ void k_head(const float* __restrict__ out, const float* __restrict__ W2,
                       const float* __restrict__ b2, float* __restrict__ y,
                       int N, int OUT) {
    int wave = (int)((blockIdx.x * (size_t)blockDim.x + threadIdx.x) >> 6);
    int lane = threadIdx.x & 63;
    if (wave >= N) return;
    float acc = 0.0f;
    if (lane < OUT) {
        acc = b2[lane];
        #pragma unroll 8
        for (int k = 0; k < HIDC; ++k)
            acc = fmaf(out[(size_t)wave * HIDC + k], W2[k * OUT + lane], acc);
    }
    float v = (lane < OUT) ? acc : -INFINITY;
    #pragma unroll
    for (int sh = 32; sh; sh >>= 1) v = fmaxf(v, __shfl_xor(v, sh, 64));
    float ex = (lane < OUT) ? __expf(acc - v) : 0.0f;
    float s = ex;
    #pragma unroll
    for (int sh = 32; sh; sh >>= 1) s += __shfl_xor(s, sh, 64);
    if (lane < OUT) y[(size_t)wave * OUT + lane] = acc - v - __logf(s);
}

extern "C" void kernel_launch(void* const* d_in, const int* in_sizes, int n_in,
                              void* d_out, int out_size, void* d_ws, size_t ws_size,
                              hipStream_t stream) {
    const float* x  = (const float*)d_in[0];
    const int*   ei = (const int*)d_in[1];
    const float* W1 = (const float*)d_in[2];
    const float* b1 = (const float*)d_in[3];
    const float* W2 = (const float*)d_in[4];
    const float* b2 = (const float*)d_in[5];
    float* y = (float*)d_out;

    const int HID = in_sizes[3];            // 64
    const int IN  = in_sizes[2] / HID;      // 256
    const int OUT = in_sizes[5];            // 40
    const int N   = in_sizes[0] / IN;       // 100000
    const int E   = in_sizes[1] / 2;        // 1.6M
    const int* rowI = ei;
    const int* colI = ei + E;

    // workspace carve-up (float-granular; all counts even => 8B alignment holds)
    float* p = (float*)d_ws;
    float* dis   = p;  p += N;
    float* alpha = p;  p += N;
    float* Mcsr  = p;  p += E;
    float* h     = p;  p += (size_t)N * HID;     // raw MLP out (beta term)
    float* out2  = p;  p += (size_t)N * HID;     // final propagate output (f32)
    u16*   sh_bf = (u16*)p;  p += (size_t)N * HID / 2;   // bf16 dis*h
    u16*   sA_bf = (u16*)p;  p += (size_t)N * HID / 2;   // bf16 dis*out1
    int*   deg     = (int*)p;  p += N;
    int*   off     = (int*)p;  p += N;
    int*   cursor  = (int*)p;  p += N;
    int*   csr_src = (int*)p;  p += E;
    int*   bsum    = (int*)p;  p += (N + 255) / 256;

    const int TPB = 256;
    const int edgeBlocks = (E + TPB - 1) / TPB;
    const int nodeBlocks = (N + TPB - 1) / TPB;
    const int nodeWaveBlocks = (N + 3) / 4;    // 4 waves/block, wave per node
    const int regDiv = (N + 7) / 8;

    // CSR build: deg -> exclusive scan -> region-grouped fill
    hipMemsetAsync(deg, 0, sizeof(int) * N, stream);
    k_deg<<<edgeBlocks, TPB, 0, stream>>>(colI, deg, E);
    k_scanA<<<nodeBlocks, TPB, 0, stream>>>(deg, bsum, N);
    k_scanB<<<1, TPB, 0, stream>>>(bsum, nodeBlocks);
    k_scanC<<<nodeBlocks, TPB, 0, stream>>>(deg, bsum, dis, off, cursor, N);
    {
        int nch = (E + FILL_CH - 1) / FILL_CH;
        k_fill2<<<8 * nch, TPB, 0, stream>>>(rowI, colI, cursor, csr_src, E, regDiv);
    }

    // front MLP (writes h f32 and sh_bf = bf16(dis*h))
    k_mlp1<<<(N + TROWS - 1) / TROWS, TPB, 0, stream>>>(x, W1, b1, dis, h, sh_bf, N);

    // iteration 1: scur = sh_bf -> writes only sA_bf (raw out1 never consumed)
    k_calcM<<<nodeWaveBlocks, TPB, 0, stream>>>(csr_src, off, deg, dis, sh_bf, Mcsr, alpha, N);
    k_gather<<<nodeWaveBlocks, TPB, 0, stream>>>(csr_src, off, deg, dis, alpha, Mcsr,
                                                 sh_bf, h, (float*)nullptr, sA_bf, N);

    // iteration 2: scur = sA_bf -> writes raw out2 (f32)
    k_calcM<<<nodeWaveBlocks, TPB, 0, stream>>>(csr_src, off, deg, dis, sA_bf, Mcsr, alpha, N);
    k_gather<<<nodeWaveBlocks, TPB, 0, stream>>>(csr_src, off, deg, dis, alpha, Mcsr,
                                                 sA_bf, h, out2, (u16*)nullptr, N);

    // output head
    k_head<<<nodeWaveBlocks, TPB, 0, stream>>>(out2, W2, b2, y, N, OUT);
}